// Round 1
// baseline (910.303 us; speedup 1.0000x reference)
//
#include <hip/hip_runtime.h>

#define NDIM 128
#define EDIM 64
#define BN_EPS 1e-5f

// ---------------------------------------------------------------------------
// Edge pass: for each edge e: msg = relu(x[src] + edge_attr[e] @ We + be),
// atomicAdd into aggr[dst]. 128 threads/block, thread j owns output feature j.
// We column j kept in 64 registers; edge_attr row is wave-uniform (scalar
// loads). Grid-stride over edges.
// ---------------------------------------------------------------------------
__global__ __launch_bounds__(128) void edge_conv(
    const float* __restrict__ xnode,   // [N,128] gather source
    const int*   __restrict__ ei,      // [2,E]
    const float* __restrict__ ea,      // [E,64]
    const float* __restrict__ We,      // [64,128]
    const float* __restrict__ be,      // [128]
    float*       __restrict__ aggr,    // [N,128] accumulate
    int E)
{
    const int j = threadIdx.x;
    float w[EDIM];
#pragma unroll
    for (int k = 0; k < EDIM; ++k) w[k] = We[k * NDIM + j];
    const float bj = be[j];

    for (int e = blockIdx.x; e < E; e += gridDim.x) {
        const int s = ei[e];
        const int d = ei[E + e];
        const float4* eap = reinterpret_cast<const float4*>(ea + (size_t)e * EDIM);
        float a0 = 0.f, a1 = 0.f, a2 = 0.f, a3 = 0.f;
#pragma unroll
        for (int k4 = 0; k4 < EDIM / 4; ++k4) {
            const float4 v = eap[k4];
            a0 += v.x * w[4 * k4 + 0];
            a1 += v.y * w[4 * k4 + 1];
            a2 += v.z * w[4 * k4 + 2];
            a3 += v.w * w[4 * k4 + 3];
        }
        float m = xnode[(size_t)s * NDIM + j] + (bj + (a0 + a1) + (a2 + a3));
        m = fmaxf(m, 0.f);
        atomicAdd(&aggr[(size_t)d * NDIM + j], m);
    }
}

// ---------------------------------------------------------------------------
// Node MLP: out = [relu]( relu((xin+aggr) @ Wa + ba) @ Wb + bb )
// Block = 256 threads = 4 waves. wave w: kh = w>>1 (k half), jh = w&1
// (feature half). Weights register-resident (64+64 per thread). Input
// broadcast via LDS float4 reads. Optionally accumulates per-feature
// sum/sumsq for BatchNorm (block partials -> atomic).
// NOTE: xin and out may alias (same rows read-then-written) - no __restrict__.
// ---------------------------------------------------------------------------
template <bool FINAL_RELU, bool STATS>
__global__ __launch_bounds__(256) void node_mlp(
    const float* xin,                   // [N,128] residual input (may alias out)
    const float* __restrict__ aggr,     // [N,128]
    const float* __restrict__ Wa, const float* __restrict__ ba,
    const float* __restrict__ Wb, const float* __restrict__ bb,
    float* out,                         // [N,128]
    float* __restrict__ stats,          // [256] (sum, sumsq) or nullptr
    int N)
{
    __shared__ __align__(16) float in_s[NDIM];
    __shared__ __align__(16) float t_s[NDIM];
    __shared__ __align__(16) float partial[NDIM];

    const int tid  = threadIdx.x;
    const int lane = tid & 63;
    const int w    = tid >> 6;
    const int kh   = w >> 1;            // 0/1: which k half
    const int jh   = w & 1;             // 0/1: which feature half
    const int jf   = jh * 64 + lane;    // output feature

    float wa[64], wb[64];
#pragma unroll
    for (int kk = 0; kk < 64; ++kk) {
        wa[kk] = Wa[(size_t)(kh * 64 + kk) * NDIM + jf];
        wb[kk] = Wb[(size_t)(kh * 64 + kk) * NDIM + jf];
    }
    const float baj = ba[jf];
    const float bbj = bb[jf];

    float ssum = 0.f, ssq = 0.f;

    for (int i = blockIdx.x; i < N; i += gridDim.x) {
        if (tid < NDIM)
            in_s[tid] = xin[(size_t)i * NDIM + tid] + aggr[(size_t)i * NDIM + tid];
        __syncthreads();

        // GEMM1 partial over this wave's k half
        float a0 = 0.f, a1 = 0.f, a2 = 0.f, a3 = 0.f;
#pragma unroll
        for (int k4 = 0; k4 < 16; ++k4) {
            const float4 v = *reinterpret_cast<const float4*>(&in_s[kh * 64 + 4 * k4]);
            a0 += v.x * wa[4 * k4 + 0];
            a1 += v.y * wa[4 * k4 + 1];
            a2 += v.z * wa[4 * k4 + 2];
            a3 += v.w * wa[4 * k4 + 3];
        }
        const float acc = (a0 + a1) + (a2 + a3);
        if (kh == 1) partial[jf] = acc;
        __syncthreads();
        if (kh == 0) {
            float t = acc + partial[jf] + baj;
            t_s[jf] = fmaxf(t, 0.f);
        }
        __syncthreads();

        // GEMM2 partial
        float c0 = 0.f, c1 = 0.f, c2 = 0.f, c3 = 0.f;
#pragma unroll
        for (int k4 = 0; k4 < 16; ++k4) {
            const float4 v = *reinterpret_cast<const float4*>(&t_s[kh * 64 + 4 * k4]);
            c0 += v.x * wb[4 * k4 + 0];
            c1 += v.y * wb[4 * k4 + 1];
            c2 += v.z * wb[4 * k4 + 2];
            c3 += v.w * wb[4 * k4 + 3];
        }
        const float acc2 = (c0 + c1) + (c2 + c3);
        if (kh == 1) partial[jf] = acc2;
        __syncthreads();
        if (kh == 0) {
            float o = acc2 + partial[jf] + bbj;
            if (FINAL_RELU) o = fmaxf(o, 0.f);
            out[(size_t)i * NDIM + jf] = o;
            if (STATS) { ssum += o; ssq += o * o; }
        }
        __syncthreads();   // protect LDS reuse next iteration
    }

    if (STATS && kh == 0) {
        atomicAdd(&stats[jf], ssum);
        atomicAdd(&stats[NDIM + jf], ssq);
    }
}

// ---------------------------------------------------------------------------
// BatchNorm apply (in place on out): out = out*scale[f] + shift[f]
// scale/shift derived from stats (sum, sumsq) once per block into LDS.
// ---------------------------------------------------------------------------
__global__ __launch_bounds__(256) void bn_apply(
    float* out,
    const float* __restrict__ stats,
    const float* __restrict__ gamma,
    const float* __restrict__ beta,
    int N)
{
    __shared__ float sc_s[NDIM];
    __shared__ float sh_s[NDIM];
    const float invN = 1.f / (float)N;
    if (threadIdx.x < NDIM) {
        const int f = threadIdx.x;
        const float mean = stats[f] * invN;
        const float var  = stats[NDIM + f] * invN - mean * mean;
        const float sc   = gamma[f] * rsqrtf(var + BN_EPS);
        sc_s[f] = sc;
        sh_s[f] = beta[f] - mean * sc;
    }
    __syncthreads();

    const int total4 = N * (NDIM / 4);
    float4* o4 = reinterpret_cast<float4*>(out);
    for (int idx = blockIdx.x * blockDim.x + threadIdx.x; idx < total4;
         idx += gridDim.x * blockDim.x) {
        const int fb = (idx & 31) * 4;
        float4 p = o4[idx];
        p.x = p.x * sc_s[fb + 0] + sh_s[fb + 0];
        p.y = p.y * sc_s[fb + 1] + sh_s[fb + 1];
        p.z = p.z * sc_s[fb + 2] + sh_s[fb + 2];
        p.w = p.w * sc_s[fb + 3] + sh_s[fb + 3];
        o4[idx] = p;
    }
}

// ---------------------------------------------------------------------------
extern "C" void kernel_launch(void* const* d_in, const int* in_sizes, int n_in,
                              void* d_out, int out_size, void* d_ws, size_t ws_size,
                              hipStream_t stream)
{
    const float* x    = (const float*)d_in[0];
    const int*   ei   = (const int*)  d_in[1];
    const float* ea   = (const float*)d_in[2];
    const float* We1  = (const float*)d_in[3];
    const float* be1  = (const float*)d_in[4];
    const float* W1   = (const float*)d_in[5];
    const float* b1   = (const float*)d_in[6];
    const float* W2   = (const float*)d_in[7];
    const float* b2   = (const float*)d_in[8];
    const float* We2  = (const float*)d_in[9];
    const float* be2  = (const float*)d_in[10];
    const float* W3   = (const float*)d_in[11];
    const float* b3   = (const float*)d_in[12];
    const float* W4   = (const float*)d_in[13];
    const float* b4   = (const float*)d_in[14];
    const float* gamma = (const float*)d_in[15];
    const float* beta  = (const float*)d_in[16];

    const int N = in_sizes[0] / NDIM;
    const int E = in_sizes[1] / 2;

    float* aggr  = (float*)d_ws;                       // [N,128]
    float* stats = aggr + (size_t)N * NDIM;            // [256]
    float* h     = (float*)d_out;                      // h / pre-BN / final out

    hipMemsetAsync(aggr, 0, (size_t)N * NDIM * sizeof(float), stream);
    hipMemsetAsync(stats, 0, 2 * NDIM * sizeof(float), stream);

    // conv1
    edge_conv<<<4096, 128, 0, stream>>>(x, ei, ea, We1, be1, aggr, E);
    node_mlp<true, false><<<2048, 256, 0, stream>>>(x, aggr, W1, b1, W2, b2,
                                                    h, nullptr, N);
    // conv2
    hipMemsetAsync(aggr, 0, (size_t)N * NDIM * sizeof(float), stream);
    edge_conv<<<4096, 128, 0, stream>>>(h, ei, ea, We2, be2, aggr, E);
    node_mlp<false, true><<<2048, 256, 0, stream>>>(h, aggr, W3, b3, W4, b4,
                                                    h, stats, N);
    // batch norm
    bn_apply<<<1024, 256, 0, stream>>>(h, stats, gamma, beta, N);
}

// Round 2
// 866.082 us; speedup vs baseline: 1.0511x; 1.0511x over previous
//
#include <hip/hip_runtime.h>

#define NDIM 128
#define EDIM 64
#define BN_EPS 1e-5f

// ---------------------------------------------------------------------------
// CSR build step 1: degree histogram over dst.
// ---------------------------------------------------------------------------
__global__ __launch_bounds__(256) void hist_k(
    const int* __restrict__ ei, int* __restrict__ deg, int E)
{
    const int e = blockIdx.x * blockDim.x + threadIdx.x;
    if (e < E) atomicAdd(&deg[ei[E + e]], 1);
}

// ---------------------------------------------------------------------------
// CSR build step 2: exclusive scan of deg -> rowptr (and cursor copy).
// Single block, 1024 threads, wave-shuffle scan (few barriers per tile).
// cursor[] holds deg on entry, start positions on exit.
// ---------------------------------------------------------------------------
__global__ __launch_bounds__(1024) void scan_build(
    int* __restrict__ cursor, int* __restrict__ rowptr, int N)
{
    __shared__ int wsums[16];
    __shared__ int run_s;
    const int tid  = threadIdx.x;
    const int lane = tid & 63;
    const int w    = tid >> 6;
    if (tid == 0) run_s = 0;
    __syncthreads();
    for (int base = 0; base < N; base += 1024) {
        const int i = base + tid;
        const int v = (i < N) ? cursor[i] : 0;
        int incl = v;
#pragma unroll
        for (int off = 1; off < 64; off <<= 1) {
            int t = __shfl_up(incl, off, 64);
            if (lane >= off) incl += t;
        }
        if (lane == 63) wsums[w] = incl;
        __syncthreads();
        if (w == 0) {
            int s = (lane < 16) ? wsums[lane] : 0;
#pragma unroll
            for (int off = 1; off < 16; off <<= 1) {
                int t = __shfl_up(s, off, 64);
                if (lane >= off) s += t;
            }
            if (lane < 16) wsums[lane] = s;   // inclusive wave sums
        }
        __syncthreads();
        const int waveoff = (w > 0) ? wsums[w - 1] : 0;
        const int run = run_s;
        const int excl = run + waveoff + incl - v;
        if (i < N) { rowptr[i] = excl; cursor[i] = excl; }
        __syncthreads();                      // all done reading run_s/wsums
        if (tid == 0) run_s += wsums[15];
        __syncthreads();                      // update visible before reuse
    }
    if (tid == 0) rowptr[N] = run_s;
}

// ---------------------------------------------------------------------------
// CSR build step 3: scatter edge ids into buckets (int atomics on cursor).
// ---------------------------------------------------------------------------
__global__ __launch_bounds__(256) void scatter_k(
    const int* __restrict__ ei, int* __restrict__ cursor,
    int* __restrict__ eid, int E)
{
    const int e = blockIdx.x * blockDim.x + threadIdx.x;
    if (e < E) {
        const int p = atomicAdd(&cursor[ei[E + e]], 1);
        eid[p] = e;
    }
}

// ---------------------------------------------------------------------------
// Edge pass (gather form): for node n, aggr[n] = sum over incoming edges of
// relu(x[src] + ea@We + be). 128 threads, thread j owns feature j; We column
// in registers; one plain store per node (NO float atomics).
// ---------------------------------------------------------------------------
__global__ __launch_bounds__(128) void edge_gather(
    const float* __restrict__ xnode,  // [N,128]
    const int*   __restrict__ ei,     // [2,E] (src = ei[0..E))
    const float* __restrict__ ea,     // [E,64]
    const int*   __restrict__ rowptr, // [N+1]
    const int*   __restrict__ eid,    // [E]
    const float* __restrict__ We,     // [64,128]
    const float* __restrict__ be,     // [128]
    float*       __restrict__ aggr,   // [N,128]
    int N)
{
    const int j = threadIdx.x;
    float w[EDIM];
#pragma unroll
    for (int k = 0; k < EDIM; ++k) w[k] = We[k * NDIM + j];
    const float bj = be[j];

    for (int n = blockIdx.x; n < N; n += gridDim.x) {
        const int p0 = rowptr[n];
        const int p1 = rowptr[n + 1];
        float acc = 0.f;
        for (int p = p0; p < p1; ++p) {
            const int e = eid[p];
            const int s = ei[e];
            const float4* eap = reinterpret_cast<const float4*>(ea + (size_t)e * EDIM);
            float a0 = 0.f, a1 = 0.f, a2 = 0.f, a3 = 0.f;
#pragma unroll
            for (int k4 = 0; k4 < EDIM / 4; ++k4) {
                const float4 v = eap[k4];
                a0 += v.x * w[4 * k4 + 0];
                a1 += v.y * w[4 * k4 + 1];
                a2 += v.z * w[4 * k4 + 2];
                a3 += v.w * w[4 * k4 + 3];
            }
            const float m = xnode[(size_t)s * NDIM + j] + (bj + (a0 + a1) + (a2 + a3));
            acc += fmaxf(m, 0.f);
        }
        aggr[(size_t)n * NDIM + j] = acc;
    }
}

// ---------------------------------------------------------------------------
// Node MLP: out = [relu]( relu((xin+aggr) @ Wa + ba) @ Wb + bb )
// Block = 256 threads = 4 waves; weights register-resident.
// ---------------------------------------------------------------------------
template <bool FINAL_RELU, bool STATS>
__global__ __launch_bounds__(256) void node_mlp(
    const float* xin,                   // may alias out
    const float* __restrict__ aggr,
    const float* __restrict__ Wa, const float* __restrict__ ba,
    const float* __restrict__ Wb, const float* __restrict__ bb,
    float* out,
    float* __restrict__ stats,
    int N)
{
    __shared__ __align__(16) float in_s[NDIM];
    __shared__ __align__(16) float t_s[NDIM];
    __shared__ __align__(16) float partial[NDIM];

    const int tid  = threadIdx.x;
    const int lane = tid & 63;
    const int w    = tid >> 6;
    const int kh   = w >> 1;
    const int jh   = w & 1;
    const int jf   = jh * 64 + lane;

    float wa[64], wb[64];
#pragma unroll
    for (int kk = 0; kk < 64; ++kk) {
        wa[kk] = Wa[(size_t)(kh * 64 + kk) * NDIM + jf];
        wb[kk] = Wb[(size_t)(kh * 64 + kk) * NDIM + jf];
    }
    const float baj = ba[jf];
    const float bbj = bb[jf];

    float ssum = 0.f, ssq = 0.f;

    for (int i = blockIdx.x; i < N; i += gridDim.x) {
        if (tid < NDIM)
            in_s[tid] = xin[(size_t)i * NDIM + tid] + aggr[(size_t)i * NDIM + tid];
        __syncthreads();

        float a0 = 0.f, a1 = 0.f, a2 = 0.f, a3 = 0.f;
#pragma unroll
        for (int k4 = 0; k4 < 16; ++k4) {
            const float4 v = *reinterpret_cast<const float4*>(&in_s[kh * 64 + 4 * k4]);
            a0 += v.x * wa[4 * k4 + 0];
            a1 += v.y * wa[4 * k4 + 1];
            a2 += v.z * wa[4 * k4 + 2];
            a3 += v.w * wa[4 * k4 + 3];
        }
        const float acc = (a0 + a1) + (a2 + a3);
        if (kh == 1) partial[jf] = acc;
        __syncthreads();
        if (kh == 0) {
            float t = acc + partial[jf] + baj;
            t_s[jf] = fmaxf(t, 0.f);
        }
        __syncthreads();

        float c0 = 0.f, c1 = 0.f, c2 = 0.f, c3 = 0.f;
#pragma unroll
        for (int k4 = 0; k4 < 16; ++k4) {
            const float4 v = *reinterpret_cast<const float4*>(&t_s[kh * 64 + 4 * k4]);
            c0 += v.x * wb[4 * k4 + 0];
            c1 += v.y * wb[4 * k4 + 1];
            c2 += v.z * wb[4 * k4 + 2];
            c3 += v.w * wb[4 * k4 + 3];
        }
        const float acc2 = (c0 + c1) + (c2 + c3);
        if (kh == 1) partial[jf] = acc2;
        __syncthreads();
        if (kh == 0) {
            float o = acc2 + partial[jf] + bbj;
            if (FINAL_RELU) o = fmaxf(o, 0.f);
            out[(size_t)i * NDIM + jf] = o;
            if (STATS) { ssum += o; ssq += o * o; }
        }
        __syncthreads();
    }

    if (STATS && kh == 0) {
        atomicAdd(&stats[jf], ssum);
        atomicAdd(&stats[NDIM + jf], ssq);
    }
}

// ---------------------------------------------------------------------------
// BatchNorm apply (in place).
// ---------------------------------------------------------------------------
__global__ __launch_bounds__(256) void bn_apply(
    float* out,
    const float* __restrict__ stats,
    const float* __restrict__ gamma,
    const float* __restrict__ beta,
    int N)
{
    __shared__ float sc_s[NDIM];
    __shared__ float sh_s[NDIM];
    const float invN = 1.f / (float)N;
    if (threadIdx.x < NDIM) {
        const int f = threadIdx.x;
        const float mean = stats[f] * invN;
        const float var  = stats[NDIM + f] * invN - mean * mean;
        const float sc   = gamma[f] * rsqrtf(var + BN_EPS);
        sc_s[f] = sc;
        sh_s[f] = beta[f] - mean * sc;
    }
    __syncthreads();

    const int total4 = N * (NDIM / 4);
    float4* o4 = reinterpret_cast<float4*>(out);
    for (int idx = blockIdx.x * blockDim.x + threadIdx.x; idx < total4;
         idx += gridDim.x * blockDim.x) {
        const int fb = (idx & 31) * 4;
        float4 p = o4[idx];
        p.x = p.x * sc_s[fb + 0] + sh_s[fb + 0];
        p.y = p.y * sc_s[fb + 1] + sh_s[fb + 1];
        p.z = p.z * sc_s[fb + 2] + sh_s[fb + 2];
        p.w = p.w * sc_s[fb + 3] + sh_s[fb + 3];
        o4[idx] = p;
    }
}

// ---------------------------------------------------------------------------
extern "C" void kernel_launch(void* const* d_in, const int* in_sizes, int n_in,
                              void* d_out, int out_size, void* d_ws, size_t ws_size,
                              hipStream_t stream)
{
    const float* x    = (const float*)d_in[0];
    const int*   ei   = (const int*)  d_in[1];
    const float* ea   = (const float*)d_in[2];
    const float* We1  = (const float*)d_in[3];
    const float* be1  = (const float*)d_in[4];
    const float* W1   = (const float*)d_in[5];
    const float* b1   = (const float*)d_in[6];
    const float* W2   = (const float*)d_in[7];
    const float* b2   = (const float*)d_in[8];
    const float* We2  = (const float*)d_in[9];
    const float* be2  = (const float*)d_in[10];
    const float* W3   = (const float*)d_in[11];
    const float* b3   = (const float*)d_in[12];
    const float* W4   = (const float*)d_in[13];
    const float* b4   = (const float*)d_in[14];
    const float* gamma = (const float*)d_in[15];
    const float* beta  = (const float*)d_in[16];

    const int N = in_sizes[0] / NDIM;
    const int E = in_sizes[1] / 2;

    // workspace layout
    float* aggr   = (float*)d_ws;                        // [N*128] f32
    int*   rowptr = (int*)(aggr + (size_t)N * NDIM);     // [N+1]
    int*   cursor = rowptr + (N + 1);                    // [N] (deg -> cursor)
    int*   eid    = cursor + N;                          // [E]
    float* stats  = (float*)(eid + E);                   // [256]
    float* h      = (float*)d_out;

    hipMemsetAsync(cursor, 0, (size_t)N * sizeof(int), stream);
    hipMemsetAsync(stats, 0, 2 * NDIM * sizeof(float), stream);

    // ---- CSR build (shared by both conv layers) ----
    hist_k<<<(E + 255) / 256, 256, 0, stream>>>(ei, cursor, E);
    scan_build<<<1, 1024, 0, stream>>>(cursor, rowptr, N);
    scatter_k<<<(E + 255) / 256, 256, 0, stream>>>(ei, cursor, eid, E);

    // ---- conv1 ----
    edge_gather<<<8192, 128, 0, stream>>>(x, ei, ea, rowptr, eid, We1, be1, aggr, N);
    node_mlp<true, false><<<2048, 256, 0, stream>>>(x, aggr, W1, b1, W2, b2,
                                                    h, nullptr, N);
    // ---- conv2 ----
    edge_gather<<<8192, 128, 0, stream>>>(h, ei, ea, rowptr, eid, We2, be2, aggr, N);
    node_mlp<false, true><<<2048, 256, 0, stream>>>(h, aggr, W3, b3, W4, b4,
                                                    h, stats, N);
    // ---- batch norm ----
    bn_apply<<<1024, 256, 0, stream>>>(h, stats, gamma, beta, N);
}